// Round 9
// baseline (253.107 us; speedup 1.0000x reference)
//
#include <hip/hip_runtime.h>
#include <hip/hip_fp16.h>

// GCN 2-layer: out = Ahat( relu( Ahat(x) W1 + b1 ) W2 ) + b2, Ahat = D^-1/2 (A+I) D^-1/2.
// N=100000, E=1.6M, dims 64->128->64.
//
// R17 post-mortem: col-prefetch pipelining WON (-5us, agg_mlp 62->57, total
// 231.8us) -- not null, so the gather has latency-chain slack, not a hard
// miss-queue wall. FETCH pinned at 83.5MB (compulsory floor, as predicted).
// First-principles model says the fill rate (1.7TB/s) is below any plausible
// random-128B ceiling => more in-flight depth should help. The one untried
// lever: DEEPER windows (R13 split 8 into 2x4; never went past 8 total).
// R18: 16-deep pipelined window (matches mean degree 16) in both agg kernels,
// explicit scalars (no arrays -> no scratch), next-16 col prefetch before the
// drain. Everything else identical to R17.
// Predicted: agg_mlp 57 -> ~44us, total ~208us. Falsifier: |delta|<=2us =>
// declare ROOFLINE next round.

#define DIM 64
#define NB 256          // dst-range buckets
#define SPAN 391        // ceil(100000/256); NB*SPAN >= N; SPAN < 512
#define BK_TILE 4096
#define BK_PER 16       // edges per thread in k_bucket

typedef _Float16 f16x8 __attribute__((ext_vector_type(8)));
typedef float f32x4 __attribute__((ext_vector_type(4)));

__device__ __forceinline__ void atomAddF(float* p, float v) {
    unsafeAtomicAdd(p, v);
}

// 8 halves (packed in float4) -> add into 8 fp32 accumulators
__device__ __forceinline__ void h8_add(const float4 v, float* acc) {
    const __half2* hp = (const __half2*)&v;
    #pragma unroll
    for (int i = 0; i < 4; ++i) {
        float2 t = __half22float2(hp[i]);
        acc[2 * i] += t.x;
        acc[2 * i + 1] += t.y;
    }
}
// 8 fp32 -> 8 halves packed in a float4
__device__ __forceinline__ float4 f8_to_h8(const float* f) {
    __half2 hh[4];
    hh[0] = __float22half2_rn(make_float2(f[0], f[1]));
    hh[1] = __float22half2_rn(make_float2(f[2], f[3]));
    hh[2] = __float22half2_rn(make_float2(f[4], f[5]));
    hh[3] = __float22half2_rn(make_float2(f[6], f[7]));
    return *(float4*)hh;
}

// CSR gather: 16-deep software-pipelined window (explicit scalars), next
// window's col indices prefetched BEFORE the drain so the dependent index
// fetch and the next gathers overlap the h8_add chain. Remainder: one 8-deep
// window, then 2/1 tails.
__device__ __forceinline__ void gather1(const float4* __restrict__ h4,
                                        const int* __restrict__ col,
                                        int e, int e1, int lane, float* accA, float* accB) {
    if (e + 16 <= e1) {
        int c0 = col[e], c1 = col[e + 1], c2 = col[e + 2], c3 = col[e + 3];
        int c4 = col[e + 4], c5 = col[e + 5], c6 = col[e + 6], c7 = col[e + 7];
        int c8 = col[e + 8], c9 = col[e + 9], c10 = col[e + 10], c11 = col[e + 11];
        int c12 = col[e + 12], c13 = col[e + 13], c14 = col[e + 14], c15 = col[e + 15];
        e += 16;
        while (true) {
            float4 v0 = h4[(long)c0 * 8 + lane];
            float4 v1 = h4[(long)c1 * 8 + lane];
            float4 v2 = h4[(long)c2 * 8 + lane];
            float4 v3 = h4[(long)c3 * 8 + lane];
            float4 v4 = h4[(long)c4 * 8 + lane];
            float4 v5 = h4[(long)c5 * 8 + lane];
            float4 v6 = h4[(long)c6 * 8 + lane];
            float4 v7 = h4[(long)c7 * 8 + lane];
            float4 v8 = h4[(long)c8 * 8 + lane];
            float4 v9 = h4[(long)c9 * 8 + lane];
            float4 v10 = h4[(long)c10 * 8 + lane];
            float4 v11 = h4[(long)c11 * 8 + lane];
            float4 v12 = h4[(long)c12 * 8 + lane];
            float4 v13 = h4[(long)c13 * 8 + lane];
            float4 v14 = h4[(long)c14 * 8 + lane];
            float4 v15 = h4[(long)c15 * 8 + lane];
            bool more = (e + 16 <= e1);
            if (more) {
                c0 = col[e]; c1 = col[e + 1]; c2 = col[e + 2]; c3 = col[e + 3];
                c4 = col[e + 4]; c5 = col[e + 5]; c6 = col[e + 6]; c7 = col[e + 7];
                c8 = col[e + 8]; c9 = col[e + 9]; c10 = col[e + 10]; c11 = col[e + 11];
                c12 = col[e + 12]; c13 = col[e + 13]; c14 = col[e + 14]; c15 = col[e + 15];
            }
            h8_add(v0, accA); h8_add(v1, accB);
            h8_add(v2, accA); h8_add(v3, accB);
            h8_add(v4, accA); h8_add(v5, accB);
            h8_add(v6, accA); h8_add(v7, accB);
            h8_add(v8, accA); h8_add(v9, accB);
            h8_add(v10, accA); h8_add(v11, accB);
            h8_add(v12, accA); h8_add(v13, accB);
            h8_add(v14, accA); h8_add(v15, accB);
            if (!more) break;
            e += 16;
        }
    }
    if (e + 8 <= e1) {          // at most once (remainder < 16)
        int c0 = col[e], c1 = col[e + 1], c2 = col[e + 2], c3 = col[e + 3];
        int c4 = col[e + 4], c5 = col[e + 5], c6 = col[e + 6], c7 = col[e + 7];
        float4 v0 = h4[(long)c0 * 8 + lane];
        float4 v1 = h4[(long)c1 * 8 + lane];
        float4 v2 = h4[(long)c2 * 8 + lane];
        float4 v3 = h4[(long)c3 * 8 + lane];
        float4 v4 = h4[(long)c4 * 8 + lane];
        float4 v5 = h4[(long)c5 * 8 + lane];
        float4 v6 = h4[(long)c6 * 8 + lane];
        float4 v7 = h4[(long)c7 * 8 + lane];
        h8_add(v0, accA); h8_add(v1, accB);
        h8_add(v2, accA); h8_add(v3, accB);
        h8_add(v4, accA); h8_add(v5, accB);
        h8_add(v6, accA); h8_add(v7, accB);
        e += 8;
    }
    for (; e + 2 <= e1; e += 2) {
        float4 v0 = h4[(long)col[e] * 8 + lane];
        float4 v1 = h4[(long)col[e + 1] * 8 + lane];
        h8_add(v0, accA); h8_add(v1, accB);
    }
    if (e < e1) h8_add(h4[(long)col[e] * 8 + lane], accA);
}

// ---------------- weight prep (+ bcnt zeroing piggyback) ----------------
// W1t[n][k] = half(W1[k][n]), W2t[n][k] = half(W2[k][n]): a lane's 8 contiguous
// k-elements of the B fragment are one 16B load.
__global__ __launch_bounds__(256) void k_wconv(const float* __restrict__ W1,
                                               const float* __restrict__ W2,
                                               _Float16* __restrict__ W1t,
                                               _Float16* __restrict__ W2t,
                                               int* __restrict__ bcnt) {
    int idx = blockIdx.x * 256 + threadIdx.x;
    if (blockIdx.x == 0) bcnt[threadIdx.x] = 0;
    if (idx < 8192) {                       // W1t: [128 n][64 k]
        int n = idx >> 6, k = idx & 63;
        W1t[idx] = (_Float16)W1[k * 128 + n];
    } else if (idx < 16384) {               // W2t: [64 n][128 k]
        int j = idx - 8192;
        int n = j >> 7, k = j & 127;
        W2t[j] = (_Float16)W2[k * 64 + n];
    }
}

// ---------------- bucket totals ----------------
__global__ __launch_bounds__(256) void k_hist256(const int* __restrict__ ei,
                                                 int* __restrict__ bucketCnt, int E) {
    __shared__ int h[NB];
    const int tid = threadIdx.x;
    h[tid] = 0;
    __syncthreads();
    const int base = blockIdx.x * BK_TILE;
    #pragma unroll
    for (int j = 0; j < BK_TILE; j += 256) {
        int e = base + j + tid;
        if (e < E) atomicAdd(&h[(unsigned)ei[E + e] / (unsigned)SPAN], 1);
    }
    __syncthreads();
    if (h[tid]) atomicAdd(&bucketCnt[tid], h[tid]);
}
__global__ __launch_bounds__(256) void k_scan_b(const int* __restrict__ bucketCnt,
                                                int* __restrict__ bucketBase,
                                                int* __restrict__ gcur) {
    __shared__ int s[NB];
    const int tid = threadIdx.x;
    int v = bucketCnt[tid];
    s[tid] = v;
    __syncthreads();
    for (int off = 1; off < NB; off <<= 1) {
        int t = (tid >= off) ? s[tid - off] : 0;
        __syncthreads();
        s[tid] += t;
        __syncthreads();
    }
    int ex = s[tid] - v;
    bucketBase[tid] = ex;
    gcur[tid] = ex;
    if (tid == NB - 1) bucketBase[NB] = s[NB - 1];
}

// Phase A: tile multisplit -> bucket-grouped packed edges ((src<<9)|local_dst).
__global__ __launch_bounds__(256) void k_bucket(const int* __restrict__ ei,
                                                int* __restrict__ gcur,
                                                unsigned* __restrict__ pairs, int E) {
    __shared__ int scn[NB];
    __shared__ int run[NB];
    __shared__ int lbase[NB];
    __shared__ int gbase[NB];
    __shared__ unsigned stage[BK_TILE];
    __shared__ unsigned char bkt[BK_TILE];
    const int tid = threadIdx.x;
    const int base = blockIdx.x * BK_TILE;

    scn[tid] = 0;
    __syncthreads();

    unsigned pv[BK_PER];
    int bv[BK_PER];
    #pragma unroll
    for (int j = 0; j < BK_PER; ++j) {
        int e = base + j * 256 + tid;
        if (e < E) {
            unsigned s = (unsigned)ei[e];
            unsigned d = (unsigned)ei[E + e];
            int b = (int)(d / (unsigned)SPAN);
            bv[j] = b;
            pv[j] = (s << 9) | (d - (unsigned)b * SPAN);
            atomicAdd(&scn[b], 1);
        } else bv[j] = -1;
    }
    __syncthreads();
    int c = scn[tid];
    for (int off = 1; off < 256; off <<= 1) {
        int t = (tid >= off) ? scn[tid - off] : 0;
        __syncthreads();
        scn[tid] += t;
        __syncthreads();
    }
    int ex = scn[tid] - c;
    lbase[tid] = ex;
    run[tid] = ex;
    if (c > 0) gbase[tid] = atomicAdd(&gcur[tid], c);
    __syncthreads();

    #pragma unroll
    for (int j = 0; j < BK_PER; ++j) {
        if (bv[j] >= 0) {
            int p = atomicAdd(&run[bv[j]], 1);
            stage[p] = pv[j];
            bkt[p] = (unsigned char)bv[j];
        }
    }
    __syncthreads();

    int total = min(BK_TILE, E - base);
    for (int i = tid; i < total; i += 256) {
        int bb = bkt[i];
        pairs[gbase[bb] + (i - lbase[bb])] = stage[i];
    }
}

// Phase B: one block per bucket. Local node hist -> scan -> row_ptr/dinv/col,
// then fused prescale Y = half(dinv ⊙ x) for this bucket's rows.
__global__ __launch_bounds__(256) void k_finish(const unsigned* __restrict__ pairs,
                                                const int* __restrict__ bucketBase,
                                                int* __restrict__ row_ptr,
                                                float* __restrict__ dinv,
                                                int* __restrict__ col,
                                                const float* __restrict__ x,
                                                __half* __restrict__ Y, int N) {
    __shared__ int lh[512];
    __shared__ int sa[512];
    __shared__ int sb[512];
    __shared__ int lcur[SPAN];
    const int tid = threadIdx.x;
    const int b = blockIdx.x;
    const int lo = b * SPAN;
    const int hi = min(lo + SPAN, N);
    const int nn = hi - lo;
    const int p0 = bucketBase[b];
    const int p1 = bucketBase[b + 1];

    for (int i = tid; i < 512; i += 256) lh[i] = 0;
    __syncthreads();
    for (int e = p0 + tid; e < p1; e += 256)
        atomicAdd(&lh[pairs[e] & 511u], 1);
    __syncthreads();
    int* cur = sa;
    int* nxt = sb;
    for (int i = tid; i < 512; i += 256) sa[i] = lh[i];
    __syncthreads();
    for (int off = 1; off < 512; off <<= 1) {
        for (int i = tid; i < 512; i += 256)
            nxt[i] = cur[i] + ((i >= off) ? cur[i - off] : 0);
        __syncthreads();
        int* t = cur; cur = nxt; nxt = t;
    }
    for (int i = tid; i < nn; i += 256) {
        int cnt  = lh[i];
        int base = p0 + cur[i] - cnt;
        row_ptr[lo + i] = base;
        lcur[i] = base;
        dinv[lo + i] = rsqrtf(1.0f + (float)cnt);   // +1 self-loop
    }
    if (b == NB - 1 && tid == 0) row_ptr[N] = p1;
    __syncthreads();
    for (int e = p0 + tid; e < p1; e += 256) {
        unsigned pr = pairs[e];
        int pos = atomicAdd(&lcur[pr & 511u], 1);
        col[pos] = (int)(pr >> 9);
    }
    // fused prescale: Y[row] = half(dinv[row] * x[row]) for rows [lo,hi).
    // lh[] still holds counts (sa/sb were the scan buffers). 8 lanes/row.
    const int seg = tid & 7;
    for (int rr = tid >> 3; rr < nn; rr += 32) {
        float di = rsqrtf(1.0f + (float)lh[rr]);
        long row = lo + rr;
        float4 a = ((const float4*)x)[row * 16 + seg * 2];
        float4 c = ((const float4*)x)[row * 16 + seg * 2 + 1];
        float f[8] = {a.x * di, a.y * di, a.z * di, a.w * di,
                      c.x * di, c.y * di, c.z * di, c.w * di};
        ((float4*)Y)[row * 8 + seg] = f8_to_h8(f);
    }
}

// ---------------- final aggregation: out = dinv[d]*(X[d]+sum X[s]) + b2 ----
// 32 nodes/block, 8 lanes/node, 16-deep pipelined gather.
__global__ __launch_bounds__(256) void k_agg_fin(const int* __restrict__ row_ptr,
                                                 const int* __restrict__ col,
                                                 const float* __restrict__ dinv,
                                                 const __half* __restrict__ ph,
                                                 const float* __restrict__ bias,
                                                 float* __restrict__ outv, int n) {
    int g = blockIdx.x * 32 + (threadIdx.x >> 3);
    if (g >= n) return;
    int lane = threadIdx.x & 7;
    const float4* h4 = (const float4*)ph;
    float accA[8] = {}, accB[8] = {};
    h8_add(h4[(long)g * 8 + lane], accA);   // self (prescaled)
    gather1(h4, col, row_ptr[g], row_ptr[g + 1], lane, accA, accB);

    float di = dinv[g];
    float r[8];
    #pragma unroll
    for (int i = 0; i < 8; ++i) r[i] = (accA[i] + accB[i]) * di;
    float4 b0 = ((const float4*)bias)[lane * 2];
    float4 b1v = ((const float4*)bias)[lane * 2 + 1];
    r[0] += b0.x; r[1] += b0.y; r[2] += b0.z; r[3] += b0.w;
    r[4] += b1v.x; r[5] += b1v.y; r[6] += b1v.z; r[7] += b1v.w;
    *(float4*)&outv[(long)g * 64 + lane * 8]     = make_float4(r[0], r[1], r[2], r[3]);
    *(float4*)&outv[(long)g * 64 + lane * 8 + 4] = make_float4(r[4], r[5], r[6], r[7]);
}

// ---------------- fused agg1 + MFMA MLP (32-row tile, 128 threads, 2 waves) ----
// X[row0..row0+32) = half( dinv ⊙ relu( (Ahat x)|tile W1 + b1 ) W2 )
// Phase 1 (agg): 16 groups x 8 lanes; group does nodes grp and grp+16
//   sequentially with the 16-deep pipelined gather; rows -> LDS Xs (stride 72).
// Phase 2 (MFMA): 2 waves, wave wv owns rows [wv*16, wv*16+16).
//   v_mfma_f32_16x16x32_f16: A row=lane&15, k=(lane>>4)*8+j; B col=lane&15, same k;
//   D col=lane&15, row=(lane>>4)*4+reg (m89/m91-verified).
// Os (output stage) aliases Xs: all Xs reads happen before the Hs barrier.
__global__ __launch_bounds__(128) void k_agg_mlp(const int* __restrict__ row_ptr,
                                                 const int* __restrict__ col,
                                                 const float* __restrict__ dinv,
                                                 const __half* __restrict__ Y,
                                                 const _Float16* __restrict__ W1t, // [128,64]
                                                 const float* __restrict__ b1,     // [128]
                                                 const _Float16* __restrict__ W2t, // [64,128]
                                                 _Float16* __restrict__ X,         // [N,64]
                                                 int M) {
    __shared__ __align__(16) _Float16 Xs[32 * 72];   // 4.6 KB (agg A-tile / out stage)
    __shared__ __align__(16) _Float16 Hs[32 * 136];  // 8.7 KB
    const int tid = threadIdx.x;
    const int row0 = blockIdx.x * 32;
    const int grp = tid >> 3;
    const int lane = tid & 7;
    const float4* h4 = (const float4*)Y;

    // ---- phase 1: aggregate nodes grp and grp+16 (sequential, 16-deep window) ----
    #pragma unroll
    for (int hh = 0; hh < 2; ++hh) {
        const int lrow = grp + hh * 16;
        const int g = row0 + lrow;
        float r[8] = {};
        if (g < M) {
            float accA[8] = {}, accB[8] = {};
            h8_add(h4[(long)g * 8 + lane], accA);   // self (prescaled)
            gather1(h4, col, row_ptr[g], row_ptr[g + 1], lane, accA, accB);
            float di = dinv[g];
            #pragma unroll
            for (int i = 0; i < 8; ++i) r[i] = (accA[i] + accB[i]) * di;
        }
        *(float4*)&Xs[lrow * 72 + lane * 8] = f8_to_h8(r);
    }
    __syncthreads();

    // ---- phase 2: MFMA MLP on the 32-row LDS tile ----
    const int wv = tid >> 6;            // 0..1
    const int l64 = tid & 63;
    const int lr = l64 & 15;
    const int lg = l64 >> 4;

    f16x8 a0 = *(const f16x8*)&Xs[(wv * 16 + lr) * 72 + lg * 8];
    f16x8 a1 = *(const f16x8*)&Xs[(wv * 16 + lr) * 72 + 32 + lg * 8];
    const _Float16* wb1 = W1t + lr * 64 + lg * 8;
    f32x4 acc[8];
    #pragma unroll
    for (int nt = 0; nt < 8; ++nt) acc[nt] = (f32x4){0.f, 0.f, 0.f, 0.f};
    #pragma unroll
    for (int nt = 0; nt < 8; ++nt) {
        f16x8 b0 = *(const f16x8*)(wb1 + nt * 1024);
        f16x8 bK = *(const f16x8*)(wb1 + nt * 1024 + 32);
        acc[nt] = __builtin_amdgcn_mfma_f32_16x16x32_f16(a0, b0, acc[nt], 0, 0, 0);
        acc[nt] = __builtin_amdgcn_mfma_f32_16x16x32_f16(a1, bK, acc[nt], 0, 0, 0);
    }
    // bias + relu -> Hs
    #pragma unroll
    for (int nt = 0; nt < 8; ++nt) {
        float bv = b1[nt * 16 + lr];
        #pragma unroll
        for (int r = 0; r < 4; ++r) {
            float h = fmaxf(acc[nt][r] + bv, 0.f);
            Hs[(wv * 16 + lg * 4 + r) * 136 + nt * 16 + lr] = (_Float16)h;
        }
    }
    __syncthreads();

    // GEMM2: K=128 in 4 steps of 32
    const _Float16* wb2 = W2t + lr * 128 + lg * 8;
    const _Float16* hrow = &Hs[(wv * 16 + lr) * 136 + lg * 8];
    f32x4 acc2[4];
    #pragma unroll
    for (int nt = 0; nt < 4; ++nt) acc2[nt] = (f32x4){0.f, 0.f, 0.f, 0.f};
    #pragma unroll
    for (int kk = 0; kk < 4; ++kk) {
        f16x8 a = *(const f16x8*)(hrow + kk * 32);
        #pragma unroll
        for (int nt = 0; nt < 4; ++nt) {
            f16x8 b = *(const f16x8*)(wb2 + nt * 2048 + kk * 32);
            acc2[nt] = __builtin_amdgcn_mfma_f32_16x16x32_f16(a, b, acc2[nt], 0, 0, 0);
        }
    }
    // scale by dinv, stage to Os (= Xs alias; Xs reads all completed pre-barrier)
    _Float16* Os = Xs;
    float sc[4];
    #pragma unroll
    for (int r = 0; r < 4; ++r) {
        int gr = row0 + wv * 16 + lg * 4 + r;
        sc[r] = (gr < M) ? dinv[gr] : 0.f;
    }
    #pragma unroll
    for (int nt = 0; nt < 4; ++nt) {
        #pragma unroll
        for (int r = 0; r < 4; ++r)
            Os[(wv * 16 + lg * 4 + r) * 72 + nt * 16 + lr] = (_Float16)(acc2[nt][r] * sc[r]);
    }
    __syncthreads();

    // coalesced store: thread t -> row t>>2, 16 halves at col (t&3)*16
    {
        int r = tid >> 2, c0 = (tid & 3) * 16;
        int gr = row0 + r;
        if (gr < M) {
            f16x8 v0 = *(const f16x8*)&Os[r * 72 + c0];
            f16x8 v1 = *(const f16x8*)&Os[r * 72 + c0 + 8];
            *(f16x8*)(X + (long)gr * 64 + c0) = v0;
            *(f16x8*)(X + (long)gr * 64 + c0 + 8) = v1;
        }
    }
}

// ---------------- fallback path (float, atomic scatter; only if ws too small) ----------------
__global__ __launch_bounds__(256) void k_init_deg(float* deg, int n) {
    int i = blockIdx.x * 256 + threadIdx.x;
    if (i < n) deg[i] = 1.0f;
}
__global__ __launch_bounds__(256) void k_count_deg(const int* __restrict__ ei, float* deg, int E) {
    int e = blockIdx.x * 256 + threadIdx.x;
    if (e < E) atomAddF(&deg[ei[E + e]], 1.0f);
}
__global__ __launch_bounds__(256) void k_rsqrt(float* deg, int n) {
    int i = blockIdx.x * 256 + threadIdx.x;
    if (i < n) deg[i] = rsqrtf(deg[i]);
}
template<bool BIAS>
__global__ __launch_bounds__(256) void k_self(const float* __restrict__ src,
                                              const float* __restrict__ dinv,
                                              const float* __restrict__ b,
                                              float* __restrict__ out, int n) {
    int g = blockIdx.x * 256 + threadIdx.x;
    int i = g >> 4, c = g & 15;
    if (i >= n) return;
    float di = dinv[i];
    float s = di * di;
    float4 v = *(const float4*)&src[(long)i * DIM + c * 4];
    float4 r = make_float4(v.x * s, v.y * s, v.z * s, v.w * s);
    if (BIAS) {
        float4 bv = *(const float4*)&b[c * 4];
        r.x += bv.x; r.y += bv.y; r.z += bv.z; r.w += bv.w;
    }
    *(float4*)&out[(long)i * DIM + c * 4] = r;
}
__global__ __launch_bounds__(256) void k_edge_agg(const int* __restrict__ ei,
                                                  const float* __restrict__ dinv,
                                                  const float* __restrict__ h,
                                                  float* __restrict__ out, int E) {
    int t = threadIdx.x;
    int e = blockIdx.x * 16 + (t >> 4);
    if (e >= E) return;
    int lane = t & 15;
    int s = ei[e];
    int d = ei[E + e];
    float norm = dinv[s] * dinv[d];
    float4 hv = *(const float4*)&h[(long)s * DIM + lane * 4];
    float* o = &out[(long)d * DIM + lane * 4];
    atomAddF(o + 0, hv.x * norm);
    atomAddF(o + 1, hv.y * norm);
    atomAddF(o + 2, hv.z * norm);
    atomAddF(o + 3, hv.w * norm);
}
// float-I/O MLP for the fallback path
__global__ __launch_bounds__(256) void k_mlp_f(const float* __restrict__ G,
                                               const float* __restrict__ W1,
                                               const float* __restrict__ b1,
                                               const float* __restrict__ W2,
                                               float* __restrict__ T, int M) {
    __shared__ float Ws[64 * 128];
    __shared__ float HA[64 * 132];
    const int tid = threadIdx.x;
    const int row0 = blockIdx.x * 64;
    const int ty = tid >> 4;
    const int tx = tid & 15;
    #pragma unroll
    for (int l = 0; l < 4; ++l) {
        int idx = l * 256 + tid;
        int r = idx >> 4, cv = idx & 15;
        int gr = row0 + r;
        float4 v = make_float4(0.f, 0.f, 0.f, 0.f);
        if (gr < M) v = *(const float4*)&G[(long)gr * DIM + cv * 4];
        *(float4*)&HA[r * 68 + cv * 4] = v;
    }
    #pragma unroll
    for (int l = 0; l < 8; ++l) {
        int idx = (l * 256 + tid) * 4;
        *(float4*)&Ws[idx] = *(const float4*)&W1[idx];
    }
    __syncthreads();
    float4 accA[4], accB[4];
    #pragma unroll
    for (int i = 0; i < 4; ++i) {
        accA[i] = make_float4(0.f, 0.f, 0.f, 0.f);
        accB[i] = make_float4(0.f, 0.f, 0.f, 0.f);
    }
    for (int k4 = 0; k4 < 64; k4 += 4) {
        float4 a[4];
        #pragma unroll
        for (int i = 0; i < 4; ++i) a[i] = *(const float4*)&HA[(ty * 4 + i) * 68 + k4];
        #pragma unroll
        for (int kk = 0; kk < 4; ++kk) {
            const float* wr = &Ws[(k4 + kk) * 128 + tx * 8];
            float4 wA = *(const float4*)wr;
            float4 wB = *(const float4*)(wr + 4);
            #pragma unroll
            for (int i = 0; i < 4; ++i) {
                float ak = (&a[i].x)[kk];
                accA[i].x += ak * wA.x; accA[i].y += ak * wA.y;
                accA[i].z += ak * wA.z; accA[i].w += ak * wA.w;
                accB[i].x += ak * wB.x; accB[i].y += ak * wB.y;
                accB[i].z += ak * wB.z; accB[i].w += ak * wB.w;
            }
        }
    }
    __syncthreads();
    {
        float4 bA = *(const float4*)&b1[tx * 8];
        float4 bB = *(const float4*)&b1[tx * 8 + 4];
        #pragma unroll
        for (int i = 0; i < 4; ++i) {
            float4 hA = make_float4(fmaxf(accA[i].x + bA.x, 0.f), fmaxf(accA[i].y + bA.y, 0.f),
                                    fmaxf(accA[i].z + bA.z, 0.f), fmaxf(accA[i].w + bA.w, 0.f));
            float4 hB = make_float4(fmaxf(accB[i].x + bB.x, 0.f), fmaxf(accB[i].y + bB.y, 0.f),
                                    fmaxf(accB[i].z + bB.z, 0.f), fmaxf(accB[i].w + bB.w, 0.f));
            *(float4*)&HA[(ty * 4 + i) * 132 + tx * 8 + 0] = hA;
            *(float4*)&HA[(ty * 4 + i) * 132 + tx * 8 + 4] = hB;
        }
    }
    #pragma unroll
    for (int l = 0; l < 8; ++l) {
        int idx = (l * 256 + tid) * 4;
        *(float4*)&Ws[idx] = *(const float4*)&W2[idx];
    }
    __syncthreads();
    float4 o[4];
    #pragma unroll
    for (int i = 0; i < 4; ++i) o[i] = make_float4(0.f, 0.f, 0.f, 0.f);
    for (int k4 = 0; k4 < 128; k4 += 4) {
        float4 a[4];
        #pragma unroll
        for (int i = 0; i < 4; ++i) a[i] = *(const float4*)&HA[(ty * 4 + i) * 132 + k4];
        #pragma unroll
        for (int kk = 0; kk < 4; ++kk) {
            float4 w = *(const float4*)&Ws[(k4 + kk) * 64 + tx * 4];
            #pragma unroll
            for (int i = 0; i < 4; ++i) {
                float ak = (&a[i].x)[kk];
                o[i].x += ak * w.x; o[i].y += ak * w.y;
                o[i].z += ak * w.z; o[i].w += ak * w.w;
            }
        }
    }
    #pragma unroll
    for (int i = 0; i < 4; ++i) {
        int gr = row0 + ty * 4 + i;
        if (gr < M) *(float4*)&T[(long)gr * DIM + tx * 4] = o[i];
    }
}

extern "C" void kernel_launch(void* const* d_in, const int* in_sizes, int n_in,
                              void* d_out, int out_size, void* d_ws, size_t ws_size,
                              hipStream_t stream) {
    const float* x  = (const float*)d_in[0];
    const int*   ei = (const int*)d_in[1];   // [2,E] int32
    const float* W1 = (const float*)d_in[2];
    const float* b1 = (const float*)d_in[3];
    const float* W2 = (const float*)d_in[4];
    const float* b2 = (const float*)d_in[5];
    float* out = (float*)d_out;

    const int N = in_sizes[0] / DIM;   // 100000
    const int E = in_sizes[1] / 2;     // 1600000

    const int gn   = (N + 255) / 256;
    const int ge   = (E + 255) / 256;
    const int gagg = (N + 31) / 32;    // 32 nodes/block (both agg kernels)
    const int gmlp = (N + 63) / 64;
    const int gbk  = (E + BK_TILE - 1) / BK_TILE;

    // ws layout (256B-aligned bump). pairs does NOT alias Y (prescale fused
    // into k_finish runs concurrently with other buckets' pairs reads).
    size_t off = 0;
    auto bump = [&](size_t bytes) { size_t o = off; off = (off + bytes + 255) & ~(size_t)255; return o; };
    size_t o_dinv   = bump((size_t)N * 4);
    size_t o_rowptr = bump((size_t)(N + 1) * 4);
    size_t o_bcnt   = bump(NB * 4);
    size_t o_bbase  = bump((NB + 1) * 4);
    size_t o_gcur   = bump(NB * 4);
    size_t o_col    = bump((size_t)E * 4);
    size_t o_X      = bump((size_t)N * DIM * 2);   // half MLP out (agg2 payload)
    size_t o_Y      = bump((size_t)N * DIM * 2);   // half prescaled x (agg1 payload)
    size_t o_pairs  = bump((size_t)E * 4);         // packed edges (dead after k_finish)
    size_t o_W1t    = bump(128 * 64 * 2);          // half W1^T
    size_t o_W2t    = bump(64 * 128 * 2);          // half W2^T
    size_t need_csr = off;                         // ~39.3 MB

    char* ws = (char*)d_ws;

    if (ws_size >= need_csr) {
        float*    dinv   = (float*)(ws + o_dinv);
        int*      rowptr = (int*)(ws + o_rowptr);
        int*      bcnt   = (int*)(ws + o_bcnt);
        int*      bbase  = (int*)(ws + o_bbase);
        int*      gcur   = (int*)(ws + o_gcur);
        int*      col    = (int*)(ws + o_col);
        __half*   X      = (__half*)(ws + o_X);
        __half*   Y      = (__half*)(ws + o_Y);
        unsigned* pairs  = (unsigned*)(ws + o_pairs);
        _Float16* W1t    = (_Float16*)(ws + o_W1t);
        _Float16* W2t    = (_Float16*)(ws + o_W2t);

        k_wconv<<<64, 256, 0, stream>>>(W1, W2, W1t, W2t, bcnt);
        k_hist256<<<gbk, 256, 0, stream>>>(ei, bcnt, E);
        k_scan_b<<<1, 256, 0, stream>>>(bcnt, bbase, gcur);
        k_bucket<<<gbk, 256, 0, stream>>>(ei, gcur, pairs, E);
        // CSR finalize + fused prescale: Y = half(dinv ⊙ x)
        k_finish<<<NB, 256, 0, stream>>>(pairs, bbase, rowptr, dinv, col, x, Y, N);
        // X = half( dinv ⊙ relu( (Ahat x) W1 + b1 ) W2 )  (fused agg1 + MFMA MLP)
        k_agg_mlp<<<gagg, 128, 0, stream>>>(rowptr, col, dinv, Y, W1t, b1, W2t,
                                            (_Float16*)X, N);
        // out = dinv[d]*(X[d] + sum X[s]) + b2
        k_agg_fin<<<gagg, 256, 0, stream>>>(rowptr, col, dinv, X, b2, out, N);
    } else {
        // -------- fallback (float atomic scatter) --------
        float* dinv = (float*)ws;
        float* buf  = (float*)(ws + 512 * 1024);
        int grow16 = ((long)N * 16 + 255) / 256;
        int gedge = (E + 15) / 16;

        k_init_deg<<<gn, 256, 0, stream>>>(dinv, N);
        k_count_deg<<<ge, 256, 0, stream>>>(ei, dinv, E);
        k_rsqrt<<<gn, 256, 0, stream>>>(dinv, N);

        k_self<false><<<grow16, 256, 0, stream>>>(x, dinv, nullptr, buf, N);
        k_edge_agg<<<gedge, 256, 0, stream>>>(ei, dinv, x, buf, E);
        k_mlp_f<<<gmlp, 256, 0, stream>>>(buf, W1, b1, W2, buf, N);
        k_self<true><<<grow16, 256, 0, stream>>>(buf, dinv, b2, out, N);
        k_edge_agg<<<gedge, 256, 0, stream>>>(ei, dinv, buf, out, E);
    }
}

// Round 10
// 231.797 us; speedup vs baseline: 1.0919x; 1.0919x over previous
//
#include <hip/hip_runtime.h>
#include <hip/hip_fp16.h>

// GCN 2-layer: out = Ahat( relu( Ahat(x) W1 + b1 ) W2 ) + b2, Ahat = D^-1/2 (A+I) D^-1/2.
// N=100000, E=1.6M, dims 64->128->64.
//
// R18 post-mortem: 16-deep window regressed (57->73.6us): VGPR 60->88 crossed
// the 64-VGPR occupancy tier, occupancy 31->17.5%. The gather optimum is
// 8-deep + col-prefetch (R17): VGPR<=64, ~10 waves/CU, issue-continuous.
// Campaign summary on the gather: ILP split (R13) X, TLP halving (R14) null,
// LDS scatter (R15) XX, L2 chunking (R16) X, depth 16 (R18) X; col-prefetch
// pipelining (R17) +5us WIN. FETCH pinned at the compulsory per-XCD floor
// (~83MB = 8 XCDs x ~11MB unique lines); fp8 payload fails the error budget.
// R19: exact revert to R17 (best known, 231.8us). This is the structural
// floor; expect ~232us, then ROOFLINE.

#define DIM 64
#define NB 256          // dst-range buckets
#define SPAN 391        // ceil(100000/256); NB*SPAN >= N; SPAN < 512
#define BK_TILE 4096
#define BK_PER 16       // edges per thread in k_bucket

typedef _Float16 f16x8 __attribute__((ext_vector_type(8)));
typedef float f32x4 __attribute__((ext_vector_type(4)));

__device__ __forceinline__ void atomAddF(float* p, float v) {
    unsafeAtomicAdd(p, v);
}

// 8 halves (packed in float4) -> add into 8 fp32 accumulators
__device__ __forceinline__ void h8_add(const float4 v, float* acc) {
    const __half2* hp = (const __half2*)&v;
    #pragma unroll
    for (int i = 0; i < 4; ++i) {
        float2 t = __half22float2(hp[i]);
        acc[2 * i] += t.x;
        acc[2 * i + 1] += t.y;
    }
}
// 8 fp32 -> 8 halves packed in a float4
__device__ __forceinline__ float4 f8_to_h8(const float* f) {
    __half2 hh[4];
    hh[0] = __float22half2_rn(make_float2(f[0], f[1]));
    hh[1] = __float22half2_rn(make_float2(f[2], f[3]));
    hh[2] = __float22half2_rn(make_float2(f[4], f[5]));
    hh[3] = __float22half2_rn(make_float2(f[6], f[7]));
    return *(float4*)hh;
}

// Single-chain 8-deep CSR gather with SOFTWARE-PIPELINED col prefetch:
// next window's 8 col indices are issued BEFORE the current window's drain,
// so the dependent index fetch overlaps the h8_add chain. (R17-proven: keeps
// VGPR <= 64; deeper windows cross the occupancy tier and regress.)
__device__ __forceinline__ void gather1(const float4* __restrict__ h4,
                                        const int* __restrict__ col,
                                        int e, int e1, int lane, float* accA, float* accB) {
    if (e + 8 <= e1) {
        int c0 = col[e], c1 = col[e + 1], c2 = col[e + 2], c3 = col[e + 3];
        int c4 = col[e + 4], c5 = col[e + 5], c6 = col[e + 6], c7 = col[e + 7];
        e += 8;
        while (true) {
            float4 v0 = h4[(long)c0 * 8 + lane];
            float4 v1 = h4[(long)c1 * 8 + lane];
            float4 v2 = h4[(long)c2 * 8 + lane];
            float4 v3 = h4[(long)c3 * 8 + lane];
            float4 v4 = h4[(long)c4 * 8 + lane];
            float4 v5 = h4[(long)c5 * 8 + lane];
            float4 v6 = h4[(long)c6 * 8 + lane];
            float4 v7 = h4[(long)c7 * 8 + lane];
            bool more = (e + 8 <= e1);
            if (more) {
                c0 = col[e]; c1 = col[e + 1]; c2 = col[e + 2]; c3 = col[e + 3];
                c4 = col[e + 4]; c5 = col[e + 5]; c6 = col[e + 6]; c7 = col[e + 7];
            }
            h8_add(v0, accA); h8_add(v1, accB);
            h8_add(v2, accA); h8_add(v3, accB);
            h8_add(v4, accA); h8_add(v5, accB);
            h8_add(v6, accA); h8_add(v7, accB);
            if (!more) break;
            e += 8;
        }
    }
    for (; e + 2 <= e1; e += 2) {
        float4 v0 = h4[(long)col[e] * 8 + lane];
        float4 v1 = h4[(long)col[e + 1] * 8 + lane];
        h8_add(v0, accA); h8_add(v1, accB);
    }
    if (e < e1) h8_add(h4[(long)col[e] * 8 + lane], accA);
}

// ---------------- weight prep (+ bcnt zeroing piggyback) ----------------
// W1t[n][k] = half(W1[k][n]), W2t[n][k] = half(W2[k][n]): a lane's 8 contiguous
// k-elements of the B fragment are one 16B load.
__global__ __launch_bounds__(256) void k_wconv(const float* __restrict__ W1,
                                               const float* __restrict__ W2,
                                               _Float16* __restrict__ W1t,
                                               _Float16* __restrict__ W2t,
                                               int* __restrict__ bcnt) {
    int idx = blockIdx.x * 256 + threadIdx.x;
    if (blockIdx.x == 0) bcnt[threadIdx.x] = 0;
    if (idx < 8192) {                       // W1t: [128 n][64 k]
        int n = idx >> 6, k = idx & 63;
        W1t[idx] = (_Float16)W1[k * 128 + n];
    } else if (idx < 16384) {               // W2t: [64 n][128 k]
        int j = idx - 8192;
        int n = j >> 7, k = j & 127;
        W2t[j] = (_Float16)W2[k * 64 + n];
    }
}

// ---------------- bucket totals ----------------
__global__ __launch_bounds__(256) void k_hist256(const int* __restrict__ ei,
                                                 int* __restrict__ bucketCnt, int E) {
    __shared__ int h[NB];
    const int tid = threadIdx.x;
    h[tid] = 0;
    __syncthreads();
    const int base = blockIdx.x * BK_TILE;
    #pragma unroll
    for (int j = 0; j < BK_TILE; j += 256) {
        int e = base + j + tid;
        if (e < E) atomicAdd(&h[(unsigned)ei[E + e] / (unsigned)SPAN], 1);
    }
    __syncthreads();
    if (h[tid]) atomicAdd(&bucketCnt[tid], h[tid]);
}
__global__ __launch_bounds__(256) void k_scan_b(const int* __restrict__ bucketCnt,
                                                int* __restrict__ bucketBase,
                                                int* __restrict__ gcur) {
    __shared__ int s[NB];
    const int tid = threadIdx.x;
    int v = bucketCnt[tid];
    s[tid] = v;
    __syncthreads();
    for (int off = 1; off < NB; off <<= 1) {
        int t = (tid >= off) ? s[tid - off] : 0;
        __syncthreads();
        s[tid] += t;
        __syncthreads();
    }
    int ex = s[tid] - v;
    bucketBase[tid] = ex;
    gcur[tid] = ex;
    if (tid == NB - 1) bucketBase[NB] = s[NB - 1];
}

// Phase A: tile multisplit -> bucket-grouped packed edges ((src<<9)|local_dst).
__global__ __launch_bounds__(256) void k_bucket(const int* __restrict__ ei,
                                                int* __restrict__ gcur,
                                                unsigned* __restrict__ pairs, int E) {
    __shared__ int scn[NB];
    __shared__ int run[NB];
    __shared__ int lbase[NB];
    __shared__ int gbase[NB];
    __shared__ unsigned stage[BK_TILE];
    __shared__ unsigned char bkt[BK_TILE];
    const int tid = threadIdx.x;
    const int base = blockIdx.x * BK_TILE;

    scn[tid] = 0;
    __syncthreads();

    unsigned pv[BK_PER];
    int bv[BK_PER];
    #pragma unroll
    for (int j = 0; j < BK_PER; ++j) {
        int e = base + j * 256 + tid;
        if (e < E) {
            unsigned s = (unsigned)ei[e];
            unsigned d = (unsigned)ei[E + e];
            int b = (int)(d / (unsigned)SPAN);
            bv[j] = b;
            pv[j] = (s << 9) | (d - (unsigned)b * SPAN);
            atomicAdd(&scn[b], 1);
        } else bv[j] = -1;
    }
    __syncthreads();
    int c = scn[tid];
    for (int off = 1; off < 256; off <<= 1) {
        int t = (tid >= off) ? scn[tid - off] : 0;
        __syncthreads();
        scn[tid] += t;
        __syncthreads();
    }
    int ex = scn[tid] - c;
    lbase[tid] = ex;
    run[tid] = ex;
    if (c > 0) gbase[tid] = atomicAdd(&gcur[tid], c);
    __syncthreads();

    #pragma unroll
    for (int j = 0; j < BK_PER; ++j) {
        if (bv[j] >= 0) {
            int p = atomicAdd(&run[bv[j]], 1);
            stage[p] = pv[j];
            bkt[p] = (unsigned char)bv[j];
        }
    }
    __syncthreads();

    int total = min(BK_TILE, E - base);
    for (int i = tid; i < total; i += 256) {
        int bb = bkt[i];
        pairs[gbase[bb] + (i - lbase[bb])] = stage[i];
    }
}

// Phase B: one block per bucket. Local node hist -> scan -> row_ptr/dinv/col,
// then fused prescale Y = half(dinv ⊙ x) for this bucket's rows.
__global__ __launch_bounds__(256) void k_finish(const unsigned* __restrict__ pairs,
                                                const int* __restrict__ bucketBase,
                                                int* __restrict__ row_ptr,
                                                float* __restrict__ dinv,
                                                int* __restrict__ col,
                                                const float* __restrict__ x,
                                                __half* __restrict__ Y, int N) {
    __shared__ int lh[512];
    __shared__ int sa[512];
    __shared__ int sb[512];
    __shared__ int lcur[SPAN];
    const int tid = threadIdx.x;
    const int b = blockIdx.x;
    const int lo = b * SPAN;
    const int hi = min(lo + SPAN, N);
    const int nn = hi - lo;
    const int p0 = bucketBase[b];
    const int p1 = bucketBase[b + 1];

    for (int i = tid; i < 512; i += 256) lh[i] = 0;
    __syncthreads();
    for (int e = p0 + tid; e < p1; e += 256)
        atomicAdd(&lh[pairs[e] & 511u], 1);
    __syncthreads();
    int* cur = sa;
    int* nxt = sb;
    for (int i = tid; i < 512; i += 256) sa[i] = lh[i];
    __syncthreads();
    for (int off = 1; off < 512; off <<= 1) {
        for (int i = tid; i < 512; i += 256)
            nxt[i] = cur[i] + ((i >= off) ? cur[i - off] : 0);
        __syncthreads();
        int* t = cur; cur = nxt; nxt = t;
    }
    for (int i = tid; i < nn; i += 256) {
        int cnt  = lh[i];
        int base = p0 + cur[i] - cnt;
        row_ptr[lo + i] = base;
        lcur[i] = base;
        dinv[lo + i] = rsqrtf(1.0f + (float)cnt);   // +1 self-loop
    }
    if (b == NB - 1 && tid == 0) row_ptr[N] = p1;
    __syncthreads();
    for (int e = p0 + tid; e < p1; e += 256) {
        unsigned pr = pairs[e];
        int pos = atomicAdd(&lcur[pr & 511u], 1);
        col[pos] = (int)(pr >> 9);
    }
    // fused prescale: Y[row] = half(dinv[row] * x[row]) for rows [lo,hi).
    // lh[] still holds counts (sa/sb were the scan buffers). 8 lanes/row.
    const int seg = tid & 7;
    for (int rr = tid >> 3; rr < nn; rr += 32) {
        float di = rsqrtf(1.0f + (float)lh[rr]);
        long row = lo + rr;
        float4 a = ((const float4*)x)[row * 16 + seg * 2];
        float4 c = ((const float4*)x)[row * 16 + seg * 2 + 1];
        float f[8] = {a.x * di, a.y * di, a.z * di, a.w * di,
                      c.x * di, c.y * di, c.z * di, c.w * di};
        ((float4*)Y)[row * 8 + seg] = f8_to_h8(f);
    }
}

// ---------------- final aggregation: out = dinv[d]*(X[d]+sum X[s]) + b2 ----
// 32 nodes/block, 8 lanes/node, pipelined 8-deep gather.
__global__ __launch_bounds__(256) void k_agg_fin(const int* __restrict__ row_ptr,
                                                 const int* __restrict__ col,
                                                 const float* __restrict__ dinv,
                                                 const __half* __restrict__ ph,
                                                 const float* __restrict__ bias,
                                                 float* __restrict__ outv, int n) {
    int g = blockIdx.x * 32 + (threadIdx.x >> 3);
    if (g >= n) return;
    int lane = threadIdx.x & 7;
    const float4* h4 = (const float4*)ph;
    float accA[8] = {}, accB[8] = {};
    h8_add(h4[(long)g * 8 + lane], accA);   // self (prescaled)
    gather1(h4, col, row_ptr[g], row_ptr[g + 1], lane, accA, accB);

    float di = dinv[g];
    float r[8];
    #pragma unroll
    for (int i = 0; i < 8; ++i) r[i] = (accA[i] + accB[i]) * di;
    float4 b0 = ((const float4*)bias)[lane * 2];
    float4 b1v = ((const float4*)bias)[lane * 2 + 1];
    r[0] += b0.x; r[1] += b0.y; r[2] += b0.z; r[3] += b0.w;
    r[4] += b1v.x; r[5] += b1v.y; r[6] += b1v.z; r[7] += b1v.w;
    *(float4*)&outv[(long)g * 64 + lane * 8]     = make_float4(r[0], r[1], r[2], r[3]);
    *(float4*)&outv[(long)g * 64 + lane * 8 + 4] = make_float4(r[4], r[5], r[6], r[7]);
}

// ---------------- fused agg1 + MFMA MLP (32-row tile, 128 threads, 2 waves) ----
// X[row0..row0+32) = half( dinv ⊙ relu( (Ahat x)|tile W1 + b1 ) W2 )
// Phase 1 (agg): 16 groups x 8 lanes; group does nodes grp and grp+16
//   sequentially with the pipelined 8-deep gather; rows -> LDS Xs (stride 72).
// Phase 2 (MFMA): 2 waves, wave wv owns rows [wv*16, wv*16+16).
//   v_mfma_f32_16x16x32_f16: A row=lane&15, k=(lane>>4)*8+j; B col=lane&15, same k;
//   D col=lane&15, row=(lane>>4)*4+reg (m89/m91-verified).
// Os (output stage) aliases Xs: all Xs reads happen before the Hs barrier.
__global__ __launch_bounds__(128) void k_agg_mlp(const int* __restrict__ row_ptr,
                                                 const int* __restrict__ col,
                                                 const float* __restrict__ dinv,
                                                 const __half* __restrict__ Y,
                                                 const _Float16* __restrict__ W1t, // [128,64]
                                                 const float* __restrict__ b1,     // [128]
                                                 const _Float16* __restrict__ W2t, // [64,128]
                                                 _Float16* __restrict__ X,         // [N,64]
                                                 int M) {
    __shared__ __align__(16) _Float16 Xs[32 * 72];   // 4.6 KB (agg A-tile / out stage)
    __shared__ __align__(16) _Float16 Hs[32 * 136];  // 8.7 KB
    const int tid = threadIdx.x;
    const int row0 = blockIdx.x * 32;
    const int grp = tid >> 3;
    const int lane = tid & 7;
    const float4* h4 = (const float4*)Y;

    // ---- phase 1: aggregate nodes grp and grp+16 (sequential, 8-deep window) ----
    #pragma unroll
    for (int hh = 0; hh < 2; ++hh) {
        const int lrow = grp + hh * 16;
        const int g = row0 + lrow;
        float r[8] = {};
        if (g < M) {
            float accA[8] = {}, accB[8] = {};
            h8_add(h4[(long)g * 8 + lane], accA);   // self (prescaled)
            gather1(h4, col, row_ptr[g], row_ptr[g + 1], lane, accA, accB);
            float di = dinv[g];
            #pragma unroll
            for (int i = 0; i < 8; ++i) r[i] = (accA[i] + accB[i]) * di;
        }
        *(float4*)&Xs[lrow * 72 + lane * 8] = f8_to_h8(r);
    }
    __syncthreads();

    // ---- phase 2: MFMA MLP on the 32-row LDS tile ----
    const int wv = tid >> 6;            // 0..1
    const int l64 = tid & 63;
    const int lr = l64 & 15;
    const int lg = l64 >> 4;

    f16x8 a0 = *(const f16x8*)&Xs[(wv * 16 + lr) * 72 + lg * 8];
    f16x8 a1 = *(const f16x8*)&Xs[(wv * 16 + lr) * 72 + 32 + lg * 8];
    const _Float16* wb1 = W1t + lr * 64 + lg * 8;
    f32x4 acc[8];
    #pragma unroll
    for (int nt = 0; nt < 8; ++nt) acc[nt] = (f32x4){0.f, 0.f, 0.f, 0.f};
    #pragma unroll
    for (int nt = 0; nt < 8; ++nt) {
        f16x8 b0 = *(const f16x8*)(wb1 + nt * 1024);
        f16x8 bK = *(const f16x8*)(wb1 + nt * 1024 + 32);
        acc[nt] = __builtin_amdgcn_mfma_f32_16x16x32_f16(a0, b0, acc[nt], 0, 0, 0);
        acc[nt] = __builtin_amdgcn_mfma_f32_16x16x32_f16(a1, bK, acc[nt], 0, 0, 0);
    }
    // bias + relu -> Hs
    #pragma unroll
    for (int nt = 0; nt < 8; ++nt) {
        float bv = b1[nt * 16 + lr];
        #pragma unroll
        for (int r = 0; r < 4; ++r) {
            float h = fmaxf(acc[nt][r] + bv, 0.f);
            Hs[(wv * 16 + lg * 4 + r) * 136 + nt * 16 + lr] = (_Float16)h;
        }
    }
    __syncthreads();

    // GEMM2: K=128 in 4 steps of 32
    const _Float16* wb2 = W2t + lr * 128 + lg * 8;
    const _Float16* hrow = &Hs[(wv * 16 + lr) * 136 + lg * 8];
    f32x4 acc2[4];
    #pragma unroll
    for (int nt = 0; nt < 4; ++nt) acc2[nt] = (f32x4){0.f, 0.f, 0.f, 0.f};
    #pragma unroll
    for (int kk = 0; kk < 4; ++kk) {
        f16x8 a = *(const f16x8*)(hrow + kk * 32);
        #pragma unroll
        for (int nt = 0; nt < 4; ++nt) {
            f16x8 b = *(const f16x8*)(wb2 + nt * 2048 + kk * 32);
            acc2[nt] = __builtin_amdgcn_mfma_f32_16x16x32_f16(a, b, acc2[nt], 0, 0, 0);
        }
    }
    // scale by dinv, stage to Os (= Xs alias; Xs reads all completed pre-barrier)
    _Float16* Os = Xs;
    float sc[4];
    #pragma unroll
    for (int r = 0; r < 4; ++r) {
        int gr = row0 + wv * 16 + lg * 4 + r;
        sc[r] = (gr < M) ? dinv[gr] : 0.f;
    }
    #pragma unroll
    for (int nt = 0; nt < 4; ++nt) {
        #pragma unroll
        for (int r = 0; r < 4; ++r)
            Os[(wv * 16 + lg * 4 + r) * 72 + nt * 16 + lr] = (_Float16)(acc2[nt][r] * sc[r]);
    }
    __syncthreads();

    // coalesced store: thread t -> row t>>2, 16 halves at col (t&3)*16
    {
        int r = tid >> 2, c0 = (tid & 3) * 16;
        int gr = row0 + r;
        if (gr < M) {
            f16x8 v0 = *(const f16x8*)&Os[r * 72 + c0];
            f16x8 v1 = *(const f16x8*)&Os[r * 72 + c0 + 8];
            *(f16x8*)(X + (long)gr * 64 + c0) = v0;
            *(f16x8*)(X + (long)gr * 64 + c0 + 8) = v1;
        }
    }
}

// ---------------- fallback path (float, atomic scatter; only if ws too small) ----------------
__global__ __launch_bounds__(256) void k_init_deg(float* deg, int n) {
    int i = blockIdx.x * 256 + threadIdx.x;
    if (i < n) deg[i] = 1.0f;
}
__global__ __launch_bounds__(256) void k_count_deg(const int* __restrict__ ei, float* deg, int E) {
    int e = blockIdx.x * 256 + threadIdx.x;
    if (e < E) atomAddF(&deg[ei[E + e]], 1.0f);
}
__global__ __launch_bounds__(256) void k_rsqrt(float* deg, int n) {
    int i = blockIdx.x * 256 + threadIdx.x;
    if (i < n) deg[i] = rsqrtf(deg[i]);
}
template<bool BIAS>
__global__ __launch_bounds__(256) void k_self(const float* __restrict__ src,
                                              const float* __restrict__ dinv,
                                              const float* __restrict__ b,
                                              float* __restrict__ out, int n) {
    int g = blockIdx.x * 256 + threadIdx.x;
    int i = g >> 4, c = g & 15;
    if (i >= n) return;
    float di = dinv[i];
    float s = di * di;
    float4 v = *(const float4*)&src[(long)i * DIM + c * 4];
    float4 r = make_float4(v.x * s, v.y * s, v.z * s, v.w * s);
    if (BIAS) {
        float4 bv = *(const float4*)&b[c * 4];
        r.x += bv.x; r.y += bv.y; r.z += bv.z; r.w += bv.w;
    }
    *(float4*)&out[(long)i * DIM + c * 4] = r;
}
__global__ __launch_bounds__(256) void k_edge_agg(const int* __restrict__ ei,
                                                  const float* __restrict__ dinv,
                                                  const float* __restrict__ h,
                                                  float* __restrict__ out, int E) {
    int t = threadIdx.x;
    int e = blockIdx.x * 16 + (t >> 4);
    if (e >= E) return;
    int lane = t & 15;
    int s = ei[e];
    int d = ei[E + e];
    float norm = dinv[s] * dinv[d];
    float4 hv = *(const float4*)&h[(long)s * DIM + lane * 4];
    float* o = &out[(long)d * DIM + lane * 4];
    atomAddF(o + 0, hv.x * norm);
    atomAddF(o + 1, hv.y * norm);
    atomAddF(o + 2, hv.z * norm);
    atomAddF(o + 3, hv.w * norm);
}
// float-I/O MLP for the fallback path
__global__ __launch_bounds__(256) void k_mlp_f(const float* __restrict__ G,
                                               const float* __restrict__ W1,
                                               const float* __restrict__ b1,
                                               const float* __restrict__ W2,
                                               float* __restrict__ T, int M) {
    __shared__ float Ws[64 * 128];
    __shared__ float HA[64 * 132];
    const int tid = threadIdx.x;
    const int row0 = blockIdx.x * 64;
    const int ty = tid >> 4;
    const int tx = tid & 15;
    #pragma unroll
    for (int l = 0; l < 4; ++l) {
        int idx = l * 256 + tid;
        int r = idx >> 4, cv = idx & 15;
        int gr = row0 + r;
        float4 v = make_float4(0.f, 0.f, 0.f, 0.f);
        if (gr < M) v = *(const float4*)&G[(long)gr * DIM + cv * 4];
        *(float4*)&HA[r * 68 + cv * 4] = v;
    }
    #pragma unroll
    for (int l = 0; l < 8; ++l) {
        int idx = (l * 256 + tid) * 4;
        *(float4*)&Ws[idx] = *(const float4*)&W1[idx];
    }
    __syncthreads();
    float4 accA[4], accB[4];
    #pragma unroll
    for (int i = 0; i < 4; ++i) {
        accA[i] = make_float4(0.f, 0.f, 0.f, 0.f);
        accB[i] = make_float4(0.f, 0.f, 0.f, 0.f);
    }
    for (int k4 = 0; k4 < 64; k4 += 4) {
        float4 a[4];
        #pragma unroll
        for (int i = 0; i < 4; ++i) a[i] = *(const float4*)&HA[(ty * 4 + i) * 68 + k4];
        #pragma unroll
        for (int kk = 0; kk < 4; ++kk) {
            const float* wr = &Ws[(k4 + kk) * 128 + tx * 8];
            float4 wA = *(const float4*)wr;
            float4 wB = *(const float4*)(wr + 4);
            #pragma unroll
            for (int i = 0; i < 4; ++i) {
                float ak = (&a[i].x)[kk];
                accA[i].x += ak * wA.x; accA[i].y += ak * wA.y;
                accA[i].z += ak * wA.z; accA[i].w += ak * wA.w;
                accB[i].x += ak * wB.x; accB[i].y += ak * wB.y;
                accB[i].z += ak * wB.z; accB[i].w += ak * wB.w;
            }
        }
    }
    __syncthreads();
    {
        float4 bA = *(const float4*)&b1[tx * 8];
        float4 bB = *(const float4*)&b1[tx * 8 + 4];
        #pragma unroll
        for (int i = 0; i < 4; ++i) {
            float4 hA = make_float4(fmaxf(accA[i].x + bA.x, 0.f), fmaxf(accA[i].y + bA.y, 0.f),
                                    fmaxf(accA[i].z + bA.z, 0.f), fmaxf(accA[i].w + bA.w, 0.f));
            float4 hB = make_float4(fmaxf(accB[i].x + bB.x, 0.f), fmaxf(accB[i].y + bB.y, 0.f),
                                    fmaxf(accB[i].z + bB.z, 0.f), fmaxf(accB[i].w + bB.w, 0.f));
            *(float4*)&HA[(ty * 4 + i) * 132 + tx * 8 + 0] = hA;
            *(float4*)&HA[(ty * 4 + i) * 132 + tx * 8 + 4] = hB;
        }
    }
    #pragma unroll
    for (int l = 0; l < 8; ++l) {
        int idx = (l * 256 + tid) * 4;
        *(float4*)&Ws[idx] = *(const float4*)&W2[idx];
    }
    __syncthreads();
    float4 o[4];
    #pragma unroll
    for (int i = 0; i < 4; ++i) o[i] = make_float4(0.f, 0.f, 0.f, 0.f);
    for (int k4 = 0; k4 < 128; k4 += 4) {
        float4 a[4];
        #pragma unroll
        for (int i = 0; i < 4; ++i) a[i] = *(const float4*)&HA[(ty * 4 + i) * 132 + k4];
        #pragma unroll
        for (int kk = 0; kk < 4; ++kk) {
            float4 w = *(const float4*)&Ws[(k4 + kk) * 64 + tx * 4];
            #pragma unroll
            for (int i = 0; i < 4; ++i) {
                float ak = (&a[i].x)[kk];
                o[i].x += ak * w.x; o[i].y += ak * w.y;
                o[i].z += ak * w.z; o[i].w += ak * w.w;
            }
        }
    }
    #pragma unroll
    for (int i = 0; i < 4; ++i) {
        int gr = row0 + ty * 4 + i;
        if (gr < M) *(float4*)&T[(long)gr * DIM + tx * 4] = o[i];
    }
}

extern "C" void kernel_launch(void* const* d_in, const int* in_sizes, int n_in,
                              void* d_out, int out_size, void* d_ws, size_t ws_size,
                              hipStream_t stream) {
    const float* x  = (const float*)d_in[0];
    const int*   ei = (const int*)d_in[1];   // [2,E] int32
    const float* W1 = (const float*)d_in[2];
    const float* b1 = (const float*)d_in[3];
    const float* W2 = (const float*)d_in[4];
    const float* b2 = (const float*)d_in[5];
    float* out = (float*)d_out;

    const int N = in_sizes[0] / DIM;   // 100000
    const int E = in_sizes[1] / 2;     // 1600000

    const int gn   = (N + 255) / 256;
    const int ge   = (E + 255) / 256;
    const int gagg = (N + 31) / 32;    // 32 nodes/block (both agg kernels)
    const int gmlp = (N + 63) / 64;
    const int gbk  = (E + BK_TILE - 1) / BK_TILE;

    // ws layout (256B-aligned bump). pairs does NOT alias Y (prescale fused
    // into k_finish runs concurrently with other buckets' pairs reads).
    size_t off = 0;
    auto bump = [&](size_t bytes) { size_t o = off; off = (off + bytes + 255) & ~(size_t)255; return o; };
    size_t o_dinv   = bump((size_t)N * 4);
    size_t o_rowptr = bump((size_t)(N + 1) * 4);
    size_t o_bcnt   = bump(NB * 4);
    size_t o_bbase  = bump((NB + 1) * 4);
    size_t o_gcur   = bump(NB * 4);
    size_t o_col    = bump((size_t)E * 4);
    size_t o_X      = bump((size_t)N * DIM * 2);   // half MLP out (agg2 payload)
    size_t o_Y      = bump((size_t)N * DIM * 2);   // half prescaled x (agg1 payload)
    size_t o_pairs  = bump((size_t)E * 4);         // packed edges (dead after k_finish)
    size_t o_W1t    = bump(128 * 64 * 2);          // half W1^T
    size_t o_W2t    = bump(64 * 128 * 2);          // half W2^T
    size_t need_csr = off;                         // ~39.3 MB

    char* ws = (char*)d_ws;

    if (ws_size >= need_csr) {
        float*    dinv   = (float*)(ws + o_dinv);
        int*      rowptr = (int*)(ws + o_rowptr);
        int*      bcnt   = (int*)(ws + o_bcnt);
        int*      bbase  = (int*)(ws + o_bbase);
        int*      gcur   = (int*)(ws + o_gcur);
        int*      col    = (int*)(ws + o_col);
        __half*   X      = (__half*)(ws + o_X);
        __half*   Y      = (__half*)(ws + o_Y);
        unsigned* pairs  = (unsigned*)(ws + o_pairs);
        _Float16* W1t    = (_Float16*)(ws + o_W1t);
        _Float16* W2t    = (_Float16*)(ws + o_W2t);

        k_wconv<<<64, 256, 0, stream>>>(W1, W2, W1t, W2t, bcnt);
        k_hist256<<<gbk, 256, 0, stream>>>(ei, bcnt, E);
        k_scan_b<<<1, 256, 0, stream>>>(bcnt, bbase, gcur);
        k_bucket<<<gbk, 256, 0, stream>>>(ei, gcur, pairs, E);
        // CSR finalize + fused prescale: Y = half(dinv ⊙ x)
        k_finish<<<NB, 256, 0, stream>>>(pairs, bbase, rowptr, dinv, col, x, Y, N);
        // X = half( dinv ⊙ relu( (Ahat x) W1 + b1 ) W2 )  (fused agg1 + MFMA MLP)
        k_agg_mlp<<<gagg, 128, 0, stream>>>(rowptr, col, dinv, Y, W1t, b1, W2t,
                                            (_Float16*)X, N);
        // out = dinv[d]*(X[d] + sum X[s]) + b2
        k_agg_fin<<<gagg, 256, 0, stream>>>(rowptr, col, dinv, X, b2, out, N);
    } else {
        // -------- fallback (float atomic scatter) --------
        float* dinv = (float*)ws;
        float* buf  = (float*)(ws + 512 * 1024);
        int grow16 = ((long)N * 16 + 255) / 256;
        int gedge = (E + 15) / 16;

        k_init_deg<<<gn, 256, 0, stream>>>(dinv, N);
        k_count_deg<<<ge, 256, 0, stream>>>(ei, dinv, E);
        k_rsqrt<<<gn, 256, 0, stream>>>(dinv, N);

        k_self<false><<<grow16, 256, 0, stream>>>(x, dinv, nullptr, buf, N);
        k_edge_agg<<<gedge, 256, 0, stream>>>(ei, dinv, x, buf, E);
        k_mlp_f<<<gmlp, 256, 0, stream>>>(buf, W1, b1, W2, buf, N);
        k_self<true><<<grow16, 256, 0, stream>>>(buf, dinv, b2, out, N);
        k_edge_agg<<<gedge, 256, 0, stream>>>(ei, dinv, buf, out, E);
    }
}